// Round 9
// baseline (179.324 us; speedup 1.0000x reference)
//
#include <hip/hip_runtime.h>
#include <math.h>

#define N_NODES 10000
#define N_EDGES 320000
#define F_IN 512
#define HID 256
#define PAD_DEG 80    // max in-degree ~60 (Poisson(32) over 10k nodes); 80 is +8.5 sigma
#define LDSTR 40      // LDS row stride in halves (32 + 8 pad, keeps 16B alignment)
#define N_TILES (157 * 4)     // 157 row-tiles x 4 col-tiles of 64x64

typedef _Float16 half8 __attribute__((ext_vector_type(8)));
typedef float floatx4 __attribute__((ext_vector_type(4)));

// ---- k_build: padded-CSR histogram+fill  +  W1 split/transpose (independent work) ----

__global__ void k_build(const int* __restrict__ ei, const float* __restrict__ W1,
                        int* __restrict__ count, int* __restrict__ csr,
                        _Float16* __restrict__ Bt_hi, _Float16* __restrict__ Bt_lo) {
    int i = blockIdx.x * blockDim.x + threadIdx.x;
    if (i < F_IN * HID) {                     // W1 [512][256] -> [256][512] hi/lo split
        int k = i >> 8, n = i & 255;
        float v = W1[i];
        _Float16 hi = (_Float16)v;
        Bt_hi[n * F_IN + k] = hi;
        Bt_lo[n * F_IN + k] = (_Float16)(v - (float)hi);
    }
    if (i < N_EDGES) {                        // padded-CSR build
        int src = ei[i];
        int dst = ei[N_EDGES + i];
        int pos = atomicAdd(&count[dst], 1);  // final value = in-degree
        csr[dst * PAD_DEG + pos] = src;
    }
}

// ---- k_gemm: h0 = feature @ W1 + b1 via 3-term fp16-split MFMA ----
// A staged+converted in LDS; B fragments read DIRECTLY from global (512 KB, L2-hot)

__global__ __launch_bounds__(256) void k_gemm(const float* __restrict__ A,
                                              const _Float16* __restrict__ Bt_hi,
                                              const _Float16* __restrict__ Bt_lo,
                                              const float* __restrict__ b1,
                                              float* __restrict__ h0) {
    __shared__ _Float16 As_hi[64 * LDSTR], As_lo[64 * LDSTR];
    const int tid = threadIdx.x;
    const int lane = tid & 63, w = tid >> 6;
    const int wm = (w >> 1) * 32, wn = (w & 1) * 32;
    const int quad = lane >> 4, l15 = lane & 15;
    const int r = tid >> 2, c = (tid & 3) << 3;      // stage 64 rows x 32 halves
    const int t = blockIdx.x;
    const int row0 = (t >> 2) * 64, col0 = (t & 3) * 64;
    floatx4 acc[2][2] = {};

    for (int k0 = 0; k0 < F_IN; k0 += 32) {
        float av[8];
        int arow = row0 + r;
        if (arow < N_NODES) {
            float4 v0 = *(const float4*)(A + (size_t)arow * F_IN + k0 + c);
            float4 v1 = *(const float4*)(A + (size_t)arow * F_IN + k0 + c + 4);
            av[0] = v0.x; av[1] = v0.y; av[2] = v0.z; av[3] = v0.w;
            av[4] = v1.x; av[5] = v1.y; av[6] = v1.z; av[7] = v1.w;
        } else {
            #pragma unroll
            for (int i = 0; i < 8; ++i) av[i] = 0.f;
        }
        half8 hhi, hlo;
        #pragma unroll
        for (int i = 0; i < 8; ++i) {
            _Float16 h = (_Float16)av[i];
            hhi[i] = h;
            hlo[i] = (_Float16)(av[i] - (float)h);
        }
        *(half8*)&As_hi[r * LDSTR + c] = hhi;
        *(half8*)&As_lo[r * LDSTR + c] = hlo;
        __syncthreads();
        half8 a_hi[2], a_lo[2], b_hi[2], b_lo[2];
        #pragma unroll
        for (int mi = 0; mi < 2; ++mi) {
            int mr = wm + mi * 16 + l15;             // A[m=lane&15][k=quad*8+j]
            a_hi[mi] = *(half8*)&As_hi[mr * LDSTR + quad * 8];
            a_lo[mi] = *(half8*)&As_lo[mr * LDSTR + quad * 8];
        }
        #pragma unroll
        for (int ni = 0; ni < 2; ++ni) {             // B[k][n] straight from L2-hot global
            size_t boff = (size_t)(col0 + wn + ni * 16 + l15) * F_IN + k0 + quad * 8;
            b_hi[ni] = *(const half8*)(Bt_hi + boff);
            b_lo[ni] = *(const half8*)(Bt_lo + boff);
        }
        #pragma unroll
        for (int mi = 0; mi < 2; ++mi)
            #pragma unroll
            for (int ni = 0; ni < 2; ++ni) {
                acc[mi][ni] = __builtin_amdgcn_mfma_f32_16x16x32_f16(a_hi[mi], b_hi[ni], acc[mi][ni], 0, 0, 0);
                acc[mi][ni] = __builtin_amdgcn_mfma_f32_16x16x32_f16(a_hi[mi], b_lo[ni], acc[mi][ni], 0, 0, 0);
                acc[mi][ni] = __builtin_amdgcn_mfma_f32_16x16x32_f16(a_lo[mi], b_hi[ni], acc[mi][ni], 0, 0, 0);
            }
        __syncthreads();
    }
    // epilogue: C/D layout col=lane&15, row=quad*4+reg
    #pragma unroll
    for (int mi = 0; mi < 2; ++mi)
        #pragma unroll
        for (int ni = 0; ni < 2; ++ni) {
            int colb = col0 + wn + ni * 16 + l15;
            float bias = b1[colb];
            #pragma unroll
            for (int reg = 0; reg < 4; ++reg) {
                int rowb = row0 + wm + mi * 16 + quad * 4 + reg;
                if (rowb < N_NODES) h0[(size_t)rowb * HID + colb] = acc[mi][ni][reg] + bias;
            }
        }
}

// ---- k_agg1: channel-split 4-pass aggregation ----
// pass p (blockIdx.y) touches only h0[:, 64p..64p+64) = 2.56 MB -> L2-resident per XCD.
// Each pass writes a partial W2-projection; relu is per-channel so the split is exact.

__global__ __launch_bounds__(256) void k_agg1(const float* __restrict__ h0,
                                              const int* __restrict__ csr,
                                              const int* __restrict__ count,
                                              const float* __restrict__ W2,
                                              float* __restrict__ u0p) {
    int n = blockIdx.x * 4 + (threadIdx.x >> 6);   // one wave per node (2500*4 = 10000)
    int lane = threadIdx.x & 63;
    int p = blockIdx.y;
    int deg = count[n];
    float degd = (float)(deg > 0 ? deg : 1);
    const int* row = csr + (size_t)n * PAD_DEG;
    const int ch = (p << 6) + lane;                // this lane's channel
    const float* hcol = h0 + ch;
    float acc0 = 0.f, acc1 = 0.f, acc2 = 0.f, acc3 = 0.f;
    int j = 0;
    for (; j + 8 <= deg; j += 8) {
        // wave-uniform metadata (broadcast); 8 independent scalar gathers in flight
        int s0 = row[j+0], s1 = row[j+1], s2 = row[j+2], s3 = row[j+3];
        int s4 = row[j+4], s5 = row[j+5], s6 = row[j+6], s7 = row[j+7];
        int c0 = count[s0], c1 = count[s1], c2 = count[s2], c3 = count[s3];
        int c4 = count[s4], c5 = count[s5], c6 = count[s6], c7 = count[s7];
        float v0 = hcol[(size_t)s0 * HID], v1 = hcol[(size_t)s1 * HID];
        float v2 = hcol[(size_t)s2 * HID], v3 = hcol[(size_t)s3 * HID];
        float v4 = hcol[(size_t)s4 * HID], v5 = hcol[(size_t)s5 * HID];
        float v6 = hcol[(size_t)s6 * HID], v7 = hcol[(size_t)s7 * HID];
        acc0 += rsqrtf((float)(c0 > 0 ? c0 : 1) * degd) * v0;
        acc1 += rsqrtf((float)(c1 > 0 ? c1 : 1) * degd) * v1;
        acc2 += rsqrtf((float)(c2 > 0 ? c2 : 1) * degd) * v2;
        acc3 += rsqrtf((float)(c3 > 0 ? c3 : 1) * degd) * v3;
        acc0 += rsqrtf((float)(c4 > 0 ? c4 : 1) * degd) * v4;
        acc1 += rsqrtf((float)(c5 > 0 ? c5 : 1) * degd) * v5;
        acc2 += rsqrtf((float)(c6 > 0 ? c6 : 1) * degd) * v6;
        acc3 += rsqrtf((float)(c7 > 0 ? c7 : 1) * degd) * v7;
    }
    for (; j < deg; ++j) {
        int s = row[j];
        int cs = count[s];
        acc0 += rsqrtf((float)(cs > 0 ? cs : 1) * degd) * hcol[(size_t)s * HID];
    }
    float a = fmaxf(acc0 + acc1 + acc2 + acc3, 0.f);   // relu(agg)_ch
    float p0 = a * W2[2 * ch];                          // partial projection
    float p1 = a * W2[2 * ch + 1];
    #pragma unroll
    for (int o = 32; o > 0; o >>= 1) {
        p0 += __shfl_down(p0, o);
        p1 += __shfl_down(p1, o);
    }
    if (lane == 0) {
        u0p[(size_t)n * 8 + p * 2]     = p0;
        u0p[(size_t)n * 8 + p * 2 + 1] = p1;
    }
}

// ---- k_agg2: sum partials (+b2), aggregate, Lorentz->Poincare pointwise ----

__global__ __launch_bounds__(256) void k_agg2(const float* __restrict__ u0p,
                                              const int* __restrict__ csr,
                                              const int* __restrict__ count,
                                              const float* __restrict__ b2,
                                              const float* __restrict__ scale,
                                              float* __restrict__ out) {
    int n = blockIdx.x * 4 + (threadIdx.x >> 6);
    int lane = threadIdx.x & 63;
    if (n >= N_NODES) return;
    int deg = count[n];
    float degd = (float)(deg > 0 ? deg : 1);
    const int* row = csr + (size_t)n * PAD_DEG;
    float b20 = b2[0], b21 = b2[1];
    float a0 = 0.f, a1 = 0.f;
    for (int j = lane; j < deg; j += 64) {
        int s = row[j];
        int cs = count[s];
        float wq = rsqrtf((float)(cs > 0 ? cs : 1) * degd);
        float4 qa = *(const float4*)(u0p + (size_t)s * 8);
        float4 qb = *(const float4*)(u0p + (size_t)s * 8 + 4);
        a0 += wq * (qa.x + qa.z + qb.x + qb.z + b20);
        a1 += wq * (qa.y + qa.w + qb.y + qb.w + b21);
    }
    #pragma unroll
    for (int o = 32; o > 0; o >>= 1) {
        a0 += __shfl_down(a0, o);
        a1 += __shfl_down(a1, o);
    }
    if (lane == 0) {
        float un = fmaxf(sqrtf(a0 * a0 + a1 * a1), 1e-15f);
        float t = tanhf(0.5f * un) / un;   // sinh/(1+cosh)==tanh(x/2), overflow-proof
        float p0 = a0 * t, p1 = a1 * t;
        float pn = fmaxf(sqrtf(p0 * p0 + p1 * p1), 1e-12f);
        float s = fminf(fmaxf(scale[0], 0.666f), 0.999f);
        p0 = p0 / pn * s; p1 = p1 / pn * s;
        float nn = fmaxf(sqrtf(p0 * p0 + p1 * p1), 1e-15f);
        if (nn > 1.0f) { p0 = p0 / nn; p1 = p1 / nn; }   // (1-1e-15)==1.0f in fp32
        out[2 * n]     = p0;
        out[2 * n + 1] = p1;
    }
}

// ---------------- launch ----------------

extern "C" void kernel_launch(void* const* d_in, const int* in_sizes, int n_in,
                              void* d_out, int out_size, void* d_ws, size_t ws_size,
                              hipStream_t stream) {
    const float* feature = (const float*)d_in[0];
    const int*   ei      = (const int*)d_in[1];
    const float* W1      = (const float*)d_in[2];
    const float* b1      = (const float*)d_in[3];
    const float* W2      = (const float*)d_in[4];
    const float* b2      = (const float*)d_in[5];
    const float* scale   = (const float*)d_in[6];
    float* out = (float*)d_out;

    // workspace layout (byte offsets, all 32B-aligned)
    char* W = (char*)d_ws;
    int*      count = (int*)W;                    // 10240 ints
    int*      csr   = (int*)(W + 40960);          // 800000 ints
    float*    h0    = (float*)(W + 3240960);      // 10000*256 fp32
    float*    u0p   = (float*)(W + 13480960);     // 10000*8 fp32 (4 passes x 2)
    _Float16* Bt_hi = (_Float16*)(W + 14760960);  // 256*512 halves
    _Float16* Bt_lo = (_Float16*)(W + 15023104);  // 256*512 halves  (~15.3 MB total)

    (void)hipMemsetAsync(count, 0, 10240 * sizeof(int), stream);

    k_build<<<dim3((N_EDGES + 255) / 256), dim3(256), 0, stream>>>(
        ei, W1, count, csr, Bt_hi, Bt_lo);
    k_gemm<<<dim3(N_TILES), dim3(256), 0, stream>>>(feature, Bt_hi, Bt_lo, b1, h0);
    k_agg1<<<dim3(2500, 4), dim3(256), 0, stream>>>(h0, csr, count, W2, u0p);
    k_agg2<<<dim3(2500), dim3(256), 0, stream>>>(u0p, csr, count, b2, scale, out);
}

// Round 10
// 169.970 us; speedup vs baseline: 1.0550x; 1.0550x over previous
//
#include <hip/hip_runtime.h>
#include <math.h>

#define N_NODES 10000
#define N_EDGES 320000
#define F_IN 512
#define HID 256
#define PAD_DEG 80    // max in-degree ~60 (Poisson(32) over 10k nodes); 80 is +8.5 sigma
#define LDSTR 40      // LDS row stride in halves (32 + 8 pad, keeps 16B alignment)
#define N_TILES (157 * 4)     // 157 row-tiles x 4 col-tiles of 64x64

typedef _Float16 half8 __attribute__((ext_vector_type(8)));
typedef float floatx4 __attribute__((ext_vector_type(4)));

__device__ __forceinline__ void fma4(float4& acc, float s, const float4& v) {
    acc.x += s * v.x; acc.y += s * v.y; acc.z += s * v.z; acc.w += s * v.w;
}

// ---- k_build: padded-CSR histogram+fill  +  W1 split/transpose (independent work) ----

__global__ void k_build(const int* __restrict__ ei, const float* __restrict__ W1,
                        int* __restrict__ count, int* __restrict__ csr,
                        _Float16* __restrict__ Bt_hi, _Float16* __restrict__ Bt_lo) {
    int i = blockIdx.x * blockDim.x + threadIdx.x;
    if (i < F_IN * HID) {                     // W1 [512][256] -> [256][512] hi/lo split
        int k = i >> 8, n = i & 255;
        float v = W1[i];
        _Float16 hi = (_Float16)v;
        Bt_hi[n * F_IN + k] = hi;
        Bt_lo[n * F_IN + k] = (_Float16)(v - (float)hi);
    }
    if (i < N_EDGES) {                        // padded-CSR build
        int src = ei[i];
        int dst = ei[N_EDGES + i];
        int pos = atomicAdd(&count[dst], 1);  // final value = in-degree
        csr[dst * PAD_DEG + pos] = src;
    }
}

// ---- k_gemm: h0 = feature @ W1 + b1 via 3-term fp16-split MFMA ----
// A staged+converted in LDS; B fragments read DIRECTLY from global (512 KB, L2-hot)

__global__ __launch_bounds__(256) void k_gemm(const float* __restrict__ A,
                                              const _Float16* __restrict__ Bt_hi,
                                              const _Float16* __restrict__ Bt_lo,
                                              const float* __restrict__ b1,
                                              float* __restrict__ h0) {
    __shared__ _Float16 As_hi[64 * LDSTR], As_lo[64 * LDSTR];
    const int tid = threadIdx.x;
    const int lane = tid & 63, w = tid >> 6;
    const int wm = (w >> 1) * 32, wn = (w & 1) * 32;
    const int quad = lane >> 4, l15 = lane & 15;
    const int r = tid >> 2, c = (tid & 3) << 3;      // stage 64 rows x 32 halves
    const int t = blockIdx.x;
    const int row0 = (t >> 2) * 64, col0 = (t & 3) * 64;
    floatx4 acc[2][2] = {};

    for (int k0 = 0; k0 < F_IN; k0 += 32) {
        float av[8];
        int arow = row0 + r;
        if (arow < N_NODES) {
            float4 v0 = *(const float4*)(A + (size_t)arow * F_IN + k0 + c);
            float4 v1 = *(const float4*)(A + (size_t)arow * F_IN + k0 + c + 4);
            av[0] = v0.x; av[1] = v0.y; av[2] = v0.z; av[3] = v0.w;
            av[4] = v1.x; av[5] = v1.y; av[6] = v1.z; av[7] = v1.w;
        } else {
            #pragma unroll
            for (int i = 0; i < 8; ++i) av[i] = 0.f;
        }
        half8 hhi, hlo;
        #pragma unroll
        for (int i = 0; i < 8; ++i) {
            _Float16 h = (_Float16)av[i];
            hhi[i] = h;
            hlo[i] = (_Float16)(av[i] - (float)h);
        }
        *(half8*)&As_hi[r * LDSTR + c] = hhi;
        *(half8*)&As_lo[r * LDSTR + c] = hlo;
        __syncthreads();
        half8 a_hi[2], a_lo[2], b_hi[2], b_lo[2];
        #pragma unroll
        for (int mi = 0; mi < 2; ++mi) {
            int mr = wm + mi * 16 + l15;             // A[m=lane&15][k=quad*8+j]
            a_hi[mi] = *(half8*)&As_hi[mr * LDSTR + quad * 8];
            a_lo[mi] = *(half8*)&As_lo[mr * LDSTR + quad * 8];
        }
        #pragma unroll
        for (int ni = 0; ni < 2; ++ni) {             // B[k][n] straight from L2-hot global
            size_t boff = (size_t)(col0 + wn + ni * 16 + l15) * F_IN + k0 + quad * 8;
            b_hi[ni] = *(const half8*)(Bt_hi + boff);
            b_lo[ni] = *(const half8*)(Bt_lo + boff);
        }
        #pragma unroll
        for (int mi = 0; mi < 2; ++mi)
            #pragma unroll
            for (int ni = 0; ni < 2; ++ni) {
                acc[mi][ni] = __builtin_amdgcn_mfma_f32_16x16x32_f16(a_hi[mi], b_hi[ni], acc[mi][ni], 0, 0, 0);
                acc[mi][ni] = __builtin_amdgcn_mfma_f32_16x16x32_f16(a_hi[mi], b_lo[ni], acc[mi][ni], 0, 0, 0);
                acc[mi][ni] = __builtin_amdgcn_mfma_f32_16x16x32_f16(a_lo[mi], b_hi[ni], acc[mi][ni], 0, 0, 0);
            }
        __syncthreads();
    }
    // epilogue: C/D layout col=lane&15, row=quad*4+reg
    #pragma unroll
    for (int mi = 0; mi < 2; ++mi)
        #pragma unroll
        for (int ni = 0; ni < 2; ++ni) {
            int colb = col0 + wn + ni * 16 + l15;
            float bias = b1[colb];
            #pragma unroll
            for (int reg = 0; reg < 4; ++reg) {
                int rowb = row0 + wm + mi * 16 + quad * 4 + reg;
                if (rowb < N_NODES) h0[(size_t)rowb * HID + colb] = acc[mi][ni][reg] + bias;
            }
        }
}

// ---- k_agg1: u0 = relu(agg(h0)) @ W2 + b2 ----
// one wave/node, float4 (16B/lane), unroll 8, 4 accumulators; weights inline from hot count[]

__global__ __launch_bounds__(256) void k_agg1(const float* __restrict__ h0,
                                              const int* __restrict__ csr,
                                              const int* __restrict__ count,
                                              const float* __restrict__ W2,
                                              const float* __restrict__ b2,
                                              float* __restrict__ u0) {
    int n = blockIdx.x * 4 + (threadIdx.x >> 6);
    int lane = threadIdx.x & 63;
    if (n >= N_NODES) return;
    int deg = count[n];
    float degd = (float)(deg > 0 ? deg : 1);
    const int* row = csr + (size_t)n * PAD_DEG;
    int off = lane << 2;
    float4 acc0 = {0,0,0,0}, acc1 = {0,0,0,0}, acc2 = {0,0,0,0}, acc3 = {0,0,0,0};
    int j = 0;
    for (; j + 8 <= deg; j += 8) {
        // wave-uniform metadata (broadcast); 8 independent 16B gathers in flight
        int s0 = row[j+0], s1 = row[j+1], s2 = row[j+2], s3 = row[j+3];
        int s4 = row[j+4], s5 = row[j+5], s6 = row[j+6], s7 = row[j+7];
        int c0 = count[s0], c1 = count[s1], c2 = count[s2], c3 = count[s3];
        int c4 = count[s4], c5 = count[s5], c6 = count[s6], c7 = count[s7];
        float4 v0 = *(const float4*)(h0 + (size_t)s0 * HID + off);
        float4 v1 = *(const float4*)(h0 + (size_t)s1 * HID + off);
        float4 v2 = *(const float4*)(h0 + (size_t)s2 * HID + off);
        float4 v3 = *(const float4*)(h0 + (size_t)s3 * HID + off);
        float4 v4 = *(const float4*)(h0 + (size_t)s4 * HID + off);
        float4 v5 = *(const float4*)(h0 + (size_t)s5 * HID + off);
        float4 v6 = *(const float4*)(h0 + (size_t)s6 * HID + off);
        float4 v7 = *(const float4*)(h0 + (size_t)s7 * HID + off);
        fma4(acc0, rsqrtf((float)(c0 > 0 ? c0 : 1) * degd), v0);
        fma4(acc1, rsqrtf((float)(c1 > 0 ? c1 : 1) * degd), v1);
        fma4(acc2, rsqrtf((float)(c2 > 0 ? c2 : 1) * degd), v2);
        fma4(acc3, rsqrtf((float)(c3 > 0 ? c3 : 1) * degd), v3);
        fma4(acc0, rsqrtf((float)(c4 > 0 ? c4 : 1) * degd), v4);
        fma4(acc1, rsqrtf((float)(c5 > 0 ? c5 : 1) * degd), v5);
        fma4(acc2, rsqrtf((float)(c6 > 0 ? c6 : 1) * degd), v6);
        fma4(acc3, rsqrtf((float)(c7 > 0 ? c7 : 1) * degd), v7);
    }
    for (; j < deg; ++j) {
        int s = row[j];
        int cs = count[s];
        float4 v = *(const float4*)(h0 + (size_t)s * HID + off);
        fma4(acc0, rsqrtf((float)(cs > 0 ? cs : 1) * degd), v);
    }
    acc0.x += acc1.x + acc2.x + acc3.x;
    acc0.y += acc1.y + acc2.y + acc3.y;
    acc0.z += acc1.z + acc2.z + acc3.z;
    acc0.w += acc1.w + acc2.w + acc3.w;
    acc0.x = fmaxf(acc0.x, 0.f); acc0.y = fmaxf(acc0.y, 0.f);
    acc0.z = fmaxf(acc0.z, 0.f); acc0.w = fmaxf(acc0.w, 0.f);
    float4 wa = *(const float4*)(W2 + (lane << 3));
    float4 wb = *(const float4*)(W2 + (lane << 3) + 4);
    float p0 = acc0.x * wa.x + acc0.y * wa.z + acc0.z * wb.x + acc0.w * wb.z;
    float p1 = acc0.x * wa.y + acc0.y * wa.w + acc0.z * wb.y + acc0.w * wb.w;
    #pragma unroll
    for (int o = 32; o > 0; o >>= 1) {
        p0 += __shfl_down(p0, o);
        p1 += __shfl_down(p1, o);
    }
    if (lane == 0) {
        u0[2 * n]     = p0 + b2[0];
        u0[2 * n + 1] = p1 + b2[1];
    }
}

// ---- k_agg2: second aggregation + Lorentz->Poincare pointwise (weights inline) ----

__global__ __launch_bounds__(256) void k_agg2(const float* __restrict__ u0,
                                              const int* __restrict__ csr,
                                              const int* __restrict__ count,
                                              const float* __restrict__ scale,
                                              float* __restrict__ out) {
    int n = blockIdx.x * 4 + (threadIdx.x >> 6);
    int lane = threadIdx.x & 63;
    if (n >= N_NODES) return;
    int deg = count[n];
    float degd = (float)(deg > 0 ? deg : 1);
    const int* row = csr + (size_t)n * PAD_DEG;
    float a0 = 0.f, a1 = 0.f;
    for (int j = lane; j < deg; j += 64) {
        int s = row[j];
        int cs = count[s];
        float wq = rsqrtf((float)(cs > 0 ? cs : 1) * degd);
        float2 uv = *(const float2*)(u0 + 2 * (size_t)s);
        a0 += wq * uv.x;
        a1 += wq * uv.y;
    }
    #pragma unroll
    for (int o = 32; o > 0; o >>= 1) {
        a0 += __shfl_down(a0, o);
        a1 += __shfl_down(a1, o);
    }
    if (lane == 0) {
        float un = fmaxf(sqrtf(a0 * a0 + a1 * a1), 1e-15f);
        float t = tanhf(0.5f * un) / un;   // sinh/(1+cosh)==tanh(x/2), overflow-proof
        float p0 = a0 * t, p1 = a1 * t;
        float pn = fmaxf(sqrtf(p0 * p0 + p1 * p1), 1e-12f);
        float s = fminf(fmaxf(scale[0], 0.666f), 0.999f);
        p0 = p0 / pn * s; p1 = p1 / pn * s;
        float nn = fmaxf(sqrtf(p0 * p0 + p1 * p1), 1e-15f);
        if (nn > 1.0f) { p0 = p0 / nn; p1 = p1 / nn; }   // (1-1e-15)==1.0f in fp32
        out[2 * n]     = p0;
        out[2 * n + 1] = p1;
    }
}

// ---------------- launch ----------------

extern "C" void kernel_launch(void* const* d_in, const int* in_sizes, int n_in,
                              void* d_out, int out_size, void* d_ws, size_t ws_size,
                              hipStream_t stream) {
    const float* feature = (const float*)d_in[0];
    const int*   ei      = (const int*)d_in[1];
    const float* W1      = (const float*)d_in[2];
    const float* b1      = (const float*)d_in[3];
    const float* W2      = (const float*)d_in[4];
    const float* b2      = (const float*)d_in[5];
    const float* scale   = (const float*)d_in[6];
    float* out = (float*)d_out;

    // workspace layout (byte offsets, all 16B-aligned)
    char* W = (char*)d_ws;
    int*      count = (int*)W;                    // 10240 ints
    int*      csr   = (int*)(W + 40960);          // 800000 ints
    float*    h0    = (float*)(W + 3240960);      // 10000*256 fp32
    float*    u0    = (float*)(W + 13480960);     // 20000 floats
    _Float16* Bt_hi = (_Float16*)(W + 13560960);  // 256*512 halves
    _Float16* Bt_lo = (_Float16*)(W + 13823104);  // 256*512 halves  (~14.1 MB total)

    (void)hipMemsetAsync(count, 0, 10240 * sizeof(int), stream);

    k_build<<<dim3((N_EDGES + 255) / 256), dim3(256), 0, stream>>>(
        ei, W1, count, csr, Bt_hi, Bt_lo);
    k_gemm<<<dim3(N_TILES), dim3(256), 0, stream>>>(feature, Bt_hi, Bt_lo, b1, h0);
    k_agg1<<<dim3((N_NODES + 3) / 4), dim3(256), 0, stream>>>(h0, csr, count, W2, b2, u0);
    k_agg2<<<dim3((N_NODES + 3) / 4), dim3(256), 0, stream>>>(u0, csr, count, scale, out);
}

// Round 11
// 153.746 us; speedup vs baseline: 1.1664x; 1.1055x over previous
//
#include <hip/hip_runtime.h>
#include <math.h>

#define N_NODES 10000
#define N_EDGES 320000
#define F_IN 512
#define HID 256
#define PAD_DEG 80    // max in-degree ~60 (Poisson(32) over 10k nodes); 80 is +8.5 sigma
#define LDSTR 40      // LDS row stride in halves (32 + 8 pad, keeps 16B alignment)
#define N_TILES (157 * 4)     // 157 row-tiles x 4 col-tiles of 64x64
#define BUILD_BLKS ((N_EDGES + 255) / 256)   // 1250

typedef _Float16 half8 __attribute__((ext_vector_type(8)));
typedef float floatx4 __attribute__((ext_vector_type(4)));

__device__ __forceinline__ void fma4(float4& acc, float s, const float4& v) {
    acc.x += s * v.x; acc.y += s * v.y; acc.z += s * v.z; acc.w += s * v.w;
}

// ---- k_pre: zero degree counters + W1 [512][256] -> transposed fp16 hi/lo split ----
// grid 512x256 = 131072 threads = F_IN*HID exactly; replaces the hipMemsetAsync node.

__global__ __launch_bounds__(256) void k_pre(const float* __restrict__ W1,
                                             int* __restrict__ count,
                                             _Float16* __restrict__ Bt_hi,
                                             _Float16* __restrict__ Bt_lo) {
    int i = blockIdx.x * blockDim.x + threadIdx.x;
    if (i < 10240) count[i] = 0;
    int k = i >> 8, n = i & 255;
    float v = W1[i];
    _Float16 hi = (_Float16)v;
    Bt_hi[n * F_IN + k] = hi;
    Bt_lo[n * F_IN + k] = (_Float16)(v - (float)hi);
}

// ---- k_combo: GEMM tiles (blocks 0..627) || CSR build (blocks 628..1877) ----
// The two halves touch disjoint data; agg1 needs both -> next kernel boundary.

__global__ __launch_bounds__(256) void k_combo(const float* __restrict__ A,
                                               const _Float16* __restrict__ Bt_hi,
                                               const _Float16* __restrict__ Bt_lo,
                                               const float* __restrict__ b1,
                                               float* __restrict__ h0,
                                               const int* __restrict__ ei,
                                               int* __restrict__ count,
                                               int* __restrict__ csr) {
    __shared__ _Float16 As_hi[64 * LDSTR], As_lo[64 * LDSTR];
    __shared__ _Float16 Bs_hi[64 * LDSTR], Bs_lo[64 * LDSTR];
    const int tid = threadIdx.x;

    if (blockIdx.x >= N_TILES) {
        // ---------- CSR build half ----------
        int e = (blockIdx.x - N_TILES) * 256 + tid;
        if (e < N_EDGES) {
            int src = ei[e];
            int dst = ei[N_EDGES + e];
            int pos = atomicAdd(&count[dst], 1);   // final value = in-degree
            csr[dst * PAD_DEG + pos] = src;
        }
        return;
    }

    // ---------- GEMM half: h0 = feature @ W1 + b1, 3-term fp16-split MFMA ----------
    const int lane = tid & 63, w = tid >> 6;
    const int wm = (w >> 1) * 32, wn = (w & 1) * 32;
    const int quad = lane >> 4, l15 = lane & 15;
    const int r = tid >> 2, c = (tid & 3) << 3;      // stage 64 rows x 32 halves
    const int t = blockIdx.x;
    const int row0 = (t >> 2) * 64, col0 = (t & 3) * 64;
    floatx4 acc[2][2] = {};

    for (int k0 = 0; k0 < F_IN; k0 += 32) {
        float av[8];
        int arow = row0 + r;
        if (arow < N_NODES) {
            float4 v0 = *(const float4*)(A + (size_t)arow * F_IN + k0 + c);
            float4 v1 = *(const float4*)(A + (size_t)arow * F_IN + k0 + c + 4);
            av[0] = v0.x; av[1] = v0.y; av[2] = v0.z; av[3] = v0.w;
            av[4] = v1.x; av[5] = v1.y; av[6] = v1.z; av[7] = v1.w;
        } else {
            #pragma unroll
            for (int i = 0; i < 8; ++i) av[i] = 0.f;
        }
        half8 hhi, hlo;
        #pragma unroll
        for (int i = 0; i < 8; ++i) {
            _Float16 h = (_Float16)av[i];
            hhi[i] = h;
            hlo[i] = (_Float16)(av[i] - (float)h);
        }
        *(half8*)&As_hi[r * LDSTR + c] = hhi;
        *(half8*)&As_lo[r * LDSTR + c] = hlo;
        *(half8*)&Bs_hi[r * LDSTR + c] = *(const half8*)(Bt_hi + (size_t)(col0 + r) * F_IN + k0 + c);
        *(half8*)&Bs_lo[r * LDSTR + c] = *(const half8*)(Bt_lo + (size_t)(col0 + r) * F_IN + k0 + c);
        __syncthreads();
        half8 a_hi[2], a_lo[2], b_hi[2], b_lo[2];
        #pragma unroll
        for (int mi = 0; mi < 2; ++mi) {
            int mr = wm + mi * 16 + l15;             // A[m=lane&15][k=quad*8+j]
            a_hi[mi] = *(half8*)&As_hi[mr * LDSTR + quad * 8];
            a_lo[mi] = *(half8*)&As_lo[mr * LDSTR + quad * 8];
        }
        #pragma unroll
        for (int ni = 0; ni < 2; ++ni) {
            int nr = wn + ni * 16 + l15;             // B[k][n] from transposed tile
            b_hi[ni] = *(half8*)&Bs_hi[nr * LDSTR + quad * 8];
            b_lo[ni] = *(half8*)&Bs_lo[nr * LDSTR + quad * 8];
        }
        #pragma unroll
        for (int mi = 0; mi < 2; ++mi)
            #pragma unroll
            for (int ni = 0; ni < 2; ++ni) {
                acc[mi][ni] = __builtin_amdgcn_mfma_f32_16x16x32_f16(a_hi[mi], b_hi[ni], acc[mi][ni], 0, 0, 0);
                acc[mi][ni] = __builtin_amdgcn_mfma_f32_16x16x32_f16(a_hi[mi], b_lo[ni], acc[mi][ni], 0, 0, 0);
                acc[mi][ni] = __builtin_amdgcn_mfma_f32_16x16x32_f16(a_lo[mi], b_hi[ni], acc[mi][ni], 0, 0, 0);
            }
        __syncthreads();
    }
    // epilogue: C/D layout col=lane&15, row=quad*4+reg
    #pragma unroll
    for (int mi = 0; mi < 2; ++mi)
        #pragma unroll
        for (int ni = 0; ni < 2; ++ni) {
            int colb = col0 + wn + ni * 16 + l15;
            float bias = b1[colb];
            #pragma unroll
            for (int reg = 0; reg < 4; ++reg) {
                int rowb = row0 + wm + mi * 16 + quad * 4 + reg;
                if (rowb < N_NODES) h0[(size_t)rowb * HID + colb] = acc[mi][ni][reg] + bias;
            }
        }
}

// ---- k_agg1: u0 = relu(agg(h0)) @ W2 + b2 ----
// one wave/node, float4 (16B/lane), unroll 8, 4 accumulators; weights inline from hot count[]

__global__ __launch_bounds__(256) void k_agg1(const float* __restrict__ h0,
                                              const int* __restrict__ csr,
                                              const int* __restrict__ count,
                                              const float* __restrict__ W2,
                                              const float* __restrict__ b2,
                                              float* __restrict__ u0) {
    int n = blockIdx.x * 4 + (threadIdx.x >> 6);
    int lane = threadIdx.x & 63;
    if (n >= N_NODES) return;
    int deg = count[n];
    float degd = (float)(deg > 0 ? deg : 1);
    const int* row = csr + (size_t)n * PAD_DEG;
    int off = lane << 2;
    float4 acc0 = {0,0,0,0}, acc1 = {0,0,0,0}, acc2 = {0,0,0,0}, acc3 = {0,0,0,0};
    int j = 0;
    for (; j + 8 <= deg; j += 8) {
        // wave-uniform metadata (broadcast); 8 independent 16B gathers in flight
        int s0 = row[j+0], s1 = row[j+1], s2 = row[j+2], s3 = row[j+3];
        int s4 = row[j+4], s5 = row[j+5], s6 = row[j+6], s7 = row[j+7];
        int c0 = count[s0], c1 = count[s1], c2 = count[s2], c3 = count[s3];
        int c4 = count[s4], c5 = count[s5], c6 = count[s6], c7 = count[s7];
        float4 v0 = *(const float4*)(h0 + (size_t)s0 * HID + off);
        float4 v1 = *(const float4*)(h0 + (size_t)s1 * HID + off);
        float4 v2 = *(const float4*)(h0 + (size_t)s2 * HID + off);
        float4 v3 = *(const float4*)(h0 + (size_t)s3 * HID + off);
        float4 v4 = *(const float4*)(h0 + (size_t)s4 * HID + off);
        float4 v5 = *(const float4*)(h0 + (size_t)s5 * HID + off);
        float4 v6 = *(const float4*)(h0 + (size_t)s6 * HID + off);
        float4 v7 = *(const float4*)(h0 + (size_t)s7 * HID + off);
        fma4(acc0, rsqrtf((float)(c0 > 0 ? c0 : 1) * degd), v0);
        fma4(acc1, rsqrtf((float)(c1 > 0 ? c1 : 1) * degd), v1);
        fma4(acc2, rsqrtf((float)(c2 > 0 ? c2 : 1) * degd), v2);
        fma4(acc3, rsqrtf((float)(c3 > 0 ? c3 : 1) * degd), v3);
        fma4(acc0, rsqrtf((float)(c4 > 0 ? c4 : 1) * degd), v4);
        fma4(acc1, rsqrtf((float)(c5 > 0 ? c5 : 1) * degd), v5);
        fma4(acc2, rsqrtf((float)(c6 > 0 ? c6 : 1) * degd), v6);
        fma4(acc3, rsqrtf((float)(c7 > 0 ? c7 : 1) * degd), v7);
    }
    for (; j < deg; ++j) {
        int s = row[j];
        int cs = count[s];
        float4 v = *(const float4*)(h0 + (size_t)s * HID + off);
        fma4(acc0, rsqrtf((float)(cs > 0 ? cs : 1) * degd), v);
    }
    acc0.x += acc1.x + acc2.x + acc3.x;
    acc0.y += acc1.y + acc2.y + acc3.y;
    acc0.z += acc1.z + acc2.z + acc3.z;
    acc0.w += acc1.w + acc2.w + acc3.w;
    acc0.x = fmaxf(acc0.x, 0.f); acc0.y = fmaxf(acc0.y, 0.f);
    acc0.z = fmaxf(acc0.z, 0.f); acc0.w = fmaxf(acc0.w, 0.f);
    float4 wa = *(const float4*)(W2 + (lane << 3));
    float4 wb = *(const float4*)(W2 + (lane << 3) + 4);
    float p0 = acc0.x * wa.x + acc0.y * wa.z + acc0.z * wb.x + acc0.w * wb.z;
    float p1 = acc0.x * wa.y + acc0.y * wa.w + acc0.z * wb.y + acc0.w * wb.w;
    #pragma unroll
    for (int o = 32; o > 0; o >>= 1) {
        p0 += __shfl_down(p0, o);
        p1 += __shfl_down(p1, o);
    }
    if (lane == 0) {
        u0[2 * n]     = p0 + b2[0];
        u0[2 * n + 1] = p1 + b2[1];
    }
}

// ---- k_agg2: second aggregation + Lorentz->Poincare pointwise (weights inline) ----

__global__ __launch_bounds__(256) void k_agg2(const float* __restrict__ u0,
                                              const int* __restrict__ csr,
                                              const int* __restrict__ count,
                                              const float* __restrict__ scale,
                                              float* __restrict__ out) {
    int n = blockIdx.x * 4 + (threadIdx.x >> 6);
    int lane = threadIdx.x & 63;
    if (n >= N_NODES) return;
    int deg = count[n];
    float degd = (float)(deg > 0 ? deg : 1);
    const int* row = csr + (size_t)n * PAD_DEG;
    float a0 = 0.f, a1 = 0.f;
    for (int j = lane; j < deg; j += 64) {
        int s = row[j];
        int cs = count[s];
        float wq = rsqrtf((float)(cs > 0 ? cs : 1) * degd);
        float2 uv = *(const float2*)(u0 + 2 * (size_t)s);
        a0 += wq * uv.x;
        a1 += wq * uv.y;
    }
    #pragma unroll
    for (int o = 32; o > 0; o >>= 1) {
        a0 += __shfl_down(a0, o);
        a1 += __shfl_down(a1, o);
    }
    if (lane == 0) {
        float un = fmaxf(sqrtf(a0 * a0 + a1 * a1), 1e-15f);
        float t = tanhf(0.5f * un) / un;   // sinh/(1+cosh)==tanh(x/2), overflow-proof
        float p0 = a0 * t, p1 = a1 * t;
        float pn = fmaxf(sqrtf(p0 * p0 + p1 * p1), 1e-12f);
        float s = fminf(fmaxf(scale[0], 0.666f), 0.999f);
        p0 = p0 / pn * s; p1 = p1 / pn * s;
        float nn = fmaxf(sqrtf(p0 * p0 + p1 * p1), 1e-15f);
        if (nn > 1.0f) { p0 = p0 / nn; p1 = p1 / nn; }   // (1-1e-15)==1.0f in fp32
        out[2 * n]     = p0;
        out[2 * n + 1] = p1;
    }
}

// ---------------- launch ----------------

extern "C" void kernel_launch(void* const* d_in, const int* in_sizes, int n_in,
                              void* d_out, int out_size, void* d_ws, size_t ws_size,
                              hipStream_t stream) {
    const float* feature = (const float*)d_in[0];
    const int*   ei      = (const int*)d_in[1];
    const float* W1      = (const float*)d_in[2];
    const float* b1      = (const float*)d_in[3];
    const float* W2      = (const float*)d_in[4];
    const float* b2      = (const float*)d_in[5];
    const float* scale   = (const float*)d_in[6];
    float* out = (float*)d_out;

    // workspace layout (byte offsets, all 16B-aligned)
    char* W = (char*)d_ws;
    int*      count = (int*)W;                    // 10240 ints
    int*      csr   = (int*)(W + 40960);          // 800000 ints
    float*    h0    = (float*)(W + 3240960);      // 10000*256 fp32
    float*    u0    = (float*)(W + 13480960);     // 20000 floats
    _Float16* Bt_hi = (_Float16*)(W + 13560960);  // 256*512 halves
    _Float16* Bt_lo = (_Float16*)(W + 13823104);  // 256*512 halves  (~14.1 MB total)

    k_pre<<<dim3(512), dim3(256), 0, stream>>>(W1, count, Bt_hi, Bt_lo);
    k_combo<<<dim3(N_TILES + BUILD_BLKS), dim3(256), 0, stream>>>(
        feature, Bt_hi, Bt_lo, b1, h0, ei, count, csr);
    k_agg1<<<dim3((N_NODES + 3) / 4), dim3(256), 0, stream>>>(h0, csr, count, W2, b2, u0);
    k_agg2<<<dim3((N_NODES + 3) / 4), dim3(256), 0, stream>>>(u0, csr, count, scale, out);
}